// Round 11
// baseline (273.738 us; speedup 1.0000x reference)
//
#include <hip/hip_runtime.h>

#define DEV __device__ __forceinline__

typedef short bf16x8 __attribute__((ext_vector_type(8)));
typedef float f32x4  __attribute__((ext_vector_type(4)));
typedef unsigned short ushort_t;

// L=577, BT=128, D=768, B=16, T=8, H=W=24, CM=192, CR=48, K=3, M=L*BT=73856

DEV unsigned short f2bf(float f) {
  unsigned u = __float_as_uint(f);
  unsigned r = (u + 0x7fffu + ((u >> 16) & 1u)) >> 16;
  return (unsigned short)r;
}

DEV unsigned cvt_pk_bf16(float a, float b) {   // {lo:bf16(a), hi:bf16(b)} RNE
  unsigned r;
  asm("v_cvt_pk_bf16_f32 %0, %1, %2" : "=v"(r) : "v"(a), "v"(b));
  return r;
}

DEV float bf2f(unsigned short b) { return __uint_as_float((unsigned)b << 16); }

DEV float silu_g(float v) { return v / (1.f + __expf(-1.702f * v)); }

DEV void gload_lds16(const void* g, void* l) {
  __builtin_amdgcn_global_load_lds(
      (const __attribute__((address_space(1))) unsigned int*)g,
      (__attribute__((address_space(3))) unsigned int*)l, 16, 0, 0);
}

// ---------------------------------------------------------------------------
// Weight prep: transpose + cast to bf16, K-contiguous rows for MFMA B frags.
// ---------------------------------------------------------------------------
__global__ __launch_bounds__(256)
void prep_kernel(const float* __restrict__ w_pre, const float* __restrict__ w_proj,
                 short* __restrict__ w_preT, short* __restrict__ w_projT) {
  int i = blockIdx.x * 256 + threadIdx.x;
  if (i < 192 * 768) {
    int n = i / 768, k = i - n * 768;
    w_preT[i] = (short)f2bf(w_pre[k * 192 + n]);
    int n2 = i / 192, k2 = i - n2 * 192;
    w_projT[i] = (short)f2bf(w_proj[k2 * 768 + n2]);
  }
}

// ---------------------------------------------------------------------------
// GEMM1 (unchanged R7 structure): h(bf16)[M x 192] = x @ w_preT + b_pre
// ---------------------------------------------------------------------------
__global__ __launch_bounds__(512, 4)
void gemm1_kernel(const float* __restrict__ Af, const short* __restrict__ Bt,
                  const float* __restrict__ bias, ushort_t* __restrict__ C) {
  constexpr int BM = 128, BK = 64, KTOT = 768, NTOT = 192, NT = 12;
  __shared__ short As[2][BM * BK];   // 2x16 KB
  __shared__ short Bs[2][192 * BK];  // 2x24 KB

  const int tid  = threadIdx.x;
  const int wave = tid >> 6, lane = tid & 63;
  const int m0 = blockIdx.x * BM;
  const int wm = wave >> 2, wn = wave & 3;
  const int lr  = lane & 15;
  const int lk8 = lane >> 4;
  const int srow = lane >> 3;
  const int schunk = lane & 7;

  f32x4 acc[4][3] = {};
  float4 areg[2][2];

  auto loadA_f32 = [&](int kt) {
    #pragma unroll
    for (int s = 0; s < 2; ++s) {
      int id = tid + s * 512;
      int r = id >> 3, c = id & 7;
      int cg = c ^ (r & 7);
      const float* p = Af + (size_t)(m0 + r) * KTOT + kt + cg * 8;
      areg[s][0] = *(const float4*)p;
      areg[s][1] = *(const float4*)(p + 4);
    }
  };
  auto cvtStoreA = [&](int buf) {
    #pragma unroll
    for (int s = 0; s < 2; ++s) {
      int id = tid + s * 512;
      int r = id >> 3, c = id & 7;
      int4 w;
      w.x = (int)cvt_pk_bf16(areg[s][0].x, areg[s][0].y);
      w.y = (int)cvt_pk_bf16(areg[s][0].z, areg[s][0].w);
      w.z = (int)cvt_pk_bf16(areg[s][1].x, areg[s][1].y);
      w.w = (int)cvt_pk_bf16(areg[s][1].z, areg[s][1].w);
      *(int4*)&As[buf][r * 64 + c * 8] = w;
    }
  };
  auto stageB = [&](int kt, int buf) {
    #pragma unroll
    for (int j = 0; j < 3; ++j) {
      int rb8 = wave * 3 + j;
      int r = rb8 * 8 + srow;
      const short* src = Bt + (size_t)r * KTOT + kt + (schunk ^ srow) * 8;
      gload_lds16(src, (char*)Bs[buf] + rb8 * 1024);
    }
  };
  auto compute = [&](int buf) {
    #pragma unroll
    for (int ks = 0; ks < 2; ++ks) {
      int kc = ks * 4 + lk8;
      bf16x8 af[4], bfv[3];
      #pragma unroll
      for (int fm = 0; fm < 4; ++fm) {
        int row = wm * 64 + fm * 16 + lr;
        af[fm] = *(const bf16x8*)&As[buf][row * 64 + (kc ^ (row & 7)) * 8];
      }
      #pragma unroll
      for (int fn = 0; fn < 3; ++fn) {
        int row = wn * 48 + fn * 16 + lr;
        bfv[fn] = *(const bf16x8*)&Bs[buf][row * 64 + (kc ^ (row & 7)) * 8];
      }
      #pragma unroll
      for (int fm = 0; fm < 4; ++fm)
        #pragma unroll
        for (int fn = 0; fn < 3; ++fn)
          acc[fm][fn] = __builtin_amdgcn_mfma_f32_16x16x32_bf16(
              bfv[fn], af[fm], acc[fm][fn], 0, 0, 0);
    }
  };

  loadA_f32(0);
  cvtStoreA(0);
  stageB(0, 0);
  loadA_f32(BK);
  asm volatile("s_waitcnt vmcnt(4) lgkmcnt(0)" ::: "memory");
  __builtin_amdgcn_s_barrier();

  #pragma unroll
  for (int t = 0; t < NT; ++t) {
    const int cur = t & 1, nxt = cur ^ 1;
    if (t + 1 < NT) {
      stageB((t + 1) * BK, nxt);
      cvtStoreA(nxt);
      if (t + 2 < NT) loadA_f32((t + 2) * BK);
    }
    compute(cur);
    if (t + 1 < NT) {
      if (t + 2 < NT)
        asm volatile("s_waitcnt vmcnt(4) lgkmcnt(0)" ::: "memory");
      else
        asm volatile("s_waitcnt vmcnt(0) lgkmcnt(0)" ::: "memory");
      __builtin_amdgcn_s_barrier();
    }
  }

  const int cb = (lane >> 4) * 4;
  #pragma unroll
  for (int fm = 0; fm < 4; ++fm) {
    int row = m0 + wm * 64 + fm * 16 + lr;
    #pragma unroll
    for (int fn = 0; fn < 3; ++fn) {
      int col = wn * 48 + fn * 16 + cb;
      float4 bv = *(const float4*)(bias + col);
      int2 w;
      w.x = (int)cvt_pk_bf16(acc[fm][fn][0] + bv.x, acc[fm][fn][1] + bv.y);
      w.y = (int)cvt_pk_bf16(acc[fm][fn][2] + bv.z, acc[fm][fn][3] + bv.w);
      *(int2*)&C[(size_t)row * NTOT + col] = w;
    }
  }
}

// ---------------------------------------------------------------------------
// d[bt][c] = mean over l=1..576 of h_bf16[(l*128+bt)*192 + c]
// ---------------------------------------------------------------------------
__global__ __launch_bounds__(384)
void reduce_d_kernel(const ushort_t* __restrict__ h, float* __restrict__ d) {
  const int bt = blockIdx.x, tid = threadIdx.x;
  const int slice = tid / 24, c8 = tid % 24;
  __shared__ float part[16][192];
  float sum[8] = {};
  #pragma unroll 4
  for (int i = 0; i < 36; ++i) {
    int l = 1 + slice * 36 + i;
    bf16x8 v = *(const bf16x8*)&h[((size_t)l * 128 + bt) * 192 + c8 * 8];
    #pragma unroll
    for (int j = 0; j < 8; ++j) sum[j] += bf2f((unsigned short)v[j]);
  }
  #pragma unroll
  for (int j = 0; j < 8; ++j) part[slice][c8 * 8 + j] = sum[j];
  __syncthreads();
  if (tid < 192) {
    float s = 0.f;
    #pragma unroll
    for (int sl = 0; sl < 16; ++sl) s += part[sl][tid];
    d[bt * 192 + tid] = s * (1.f / 576.f);
  }
}

// ---------------------------------------------------------------------------
// Small path (unchanged): one block per b, 256 thr, LDS-staged bf16 weights.
// ---------------------------------------------------------------------------
__global__ __launch_bounds__(256)
void small_path_kernel(const float* __restrict__ d,
                       const float* __restrict__ w_g, const float* __restrict__ b_g,
                       const float* __restrict__ w_a, const float* __restrict__ b_a,
                       const float* __restrict__ w_b,
                       float* __restrict__ alpha) {
  const int b = blockIdx.x, tid = threadIdx.x;
  __shared__ unsigned short wg_buf[36864];   // 72 KB (w_g, then w_b)
  __shared__ unsigned short wa_buf[27648];   // 54 KB
  __shared__ float e[8][192];
  __shared__ float md[192];
  __shared__ float a[8][48];

  #pragma unroll
  for (int it = 0; it < 36; ++it) {
    int i = tid + it * 256;
    float4 v = *(const float4*)(w_g + i * 4);
    int2 w;
    w.x = (int)cvt_pk_bf16(v.x, v.y);
    w.y = (int)cvt_pk_bf16(v.z, v.w);
    *(int2*)&wg_buf[i * 4] = w;
  }
  #pragma unroll
  for (int it = 0; it < 27; ++it) {
    int i = tid + it * 256;
    float4 v = *(const float4*)(w_a + i * 4);
    int2 w;
    w.x = (int)cvt_pk_bf16(v.x, v.y);
    w.y = (int)cvt_pk_bf16(v.z, v.w);
    *(int2*)&wa_buf[i * 4] = w;
  }
  for (int i = tid; i < 384; i += 256)
    *(float4*)((float*)e + i * 4) = *(const float4*)(d + (size_t)b * 1536 + i * 4);
  __syncthreads();

  if (tid < 192) {
    float m = 0.f;
    #pragma unroll
    for (int t = 0; t < 8; ++t) m += e[t][tid];
    md[tid] = m * 0.125f;
  }
  __syncthreads();

  if (tid < 192) {
    float accg = b_g[tid];
    #pragma unroll 8
    for (int k = 0; k < 192; ++k)
      accg += md[k] * bf2f(wg_buf[k * 192 + tid]);
    #pragma unroll
    for (int t = 0; t < 8; ++t) e[t][tid] += accg;
  }
  __syncthreads();

  #pragma unroll
  for (int it = 0; it < 27; ++it) {
    int i = tid + it * 256;
    float4 v = *(const float4*)(w_b + i * 4);
    int2 w;
    w.x = (int)cvt_pk_bf16(v.x, v.y);
    w.y = (int)cvt_pk_bf16(v.z, v.w);
    *(int2*)&wg_buf[i * 4] = w;
  }
  for (int o = tid; o < 384; o += 256) {
    int t = o / 48, r = o - t * 48;
    float acc = b_a[r];
    #pragma unroll
    for (int dt = 0; dt < 3; ++dt) {
      int tt = t + dt - 1;
      if ((unsigned)tt < 8u) {
        #pragma unroll 8
        for (int k = 0; k < 192; ++k)
          acc += e[tt][k] * bf2f(wa_buf[(dt * 192 + k) * 48 + r]);
      }
    }
    a[t][r] = fmaxf(acc, 0.f);
  }
  __syncthreads();

  if (tid < 192) {
    #pragma unroll
    for (int t = 0; t < 8; ++t) {
      float acc = 1.0f;
      #pragma unroll
      for (int dt = 0; dt < 3; ++dt) {
        int tt = t + dt - 1;
        if ((unsigned)tt < 8u) {
          #pragma unroll 8
          for (int r = 0; r < 48; ++r)
            acc += a[tt][r] * bf2f(wg_buf[(dt * 48 + r) * 192 + tid]);
        }
      }
      alpha[(size_t)(b * 8 + t) * 192 + tid] = acc;
    }
  }
}

// ---------------------------------------------------------------------------
// FUSED dwconv+SiLU+GEMM2 (R10 structure, PLAIN stores - no NT).
// BM=64, grid (577 l x 2), 512 thr = 8 waves (2M x 4N), wave tile 32x48.
// LDS = Stile only (24 KB). Phase 2 barrier-free, B straight from L2.
// Plain stores retire via L2/L3 (out=227MB fits 256MB L3) -> cheap vmcnt
// drains and deferred writeback.
// ---------------------------------------------------------------------------
__global__ __launch_bounds__(512, 4)
void fused_out_kernel(const ushort_t* __restrict__ h, const float* __restrict__ alpha,
                      const float* __restrict__ w_base, const float* __restrict__ b_conv,
                      const short* __restrict__ Bt, const float* __restrict__ bias,
                      float* __restrict__ out) {
  constexpr int NTOT = 768;
  __shared__ ushort_t Stile[64 * 192];   // 24 KB, swizzled 16B chunks

  const int tid  = threadIdx.x;
  const int l    = blockIdx.x >> 1;
  const int bt0  = (blockIdx.x & 1) * 64;
  const int wave = tid >> 6, lane = tid & 63;
  const int wm = wave >> 2, wn = wave & 3;
  const int lr = lane & 15, lk8 = lane >> 4;

  // ---- phase 1: s-subtile (64 bt rows x 192 c) ----
  const int row = tid >> 3;               // 0..63
  const int cg  = tid & 7;
  const int bt  = bt0 + row;
  if (l == 0) {
    #pragma unroll
    for (int j = 0; j < 3; ++j) {
      int c8 = cg + 8 * j;                // 0..23
      bf16x8 hv = *(const bf16x8*)&h[(size_t)bt * 192 + c8 * 8];
      float v0 = silu_g(bf2f((ushort_t)hv[0])), v1 = silu_g(bf2f((ushort_t)hv[1]));
      float v2 = silu_g(bf2f((ushort_t)hv[2])), v3 = silu_g(bf2f((ushort_t)hv[3]));
      float v4 = silu_g(bf2f((ushort_t)hv[4])), v5 = silu_g(bf2f((ushort_t)hv[5]));
      float v6 = silu_g(bf2f((ushort_t)hv[6])), v7 = silu_g(bf2f((ushort_t)hv[7]));
      int4 pk;
      pk.x = (int)cvt_pk_bf16(v0, v1); pk.y = (int)cvt_pk_bf16(v2, v3);
      pk.z = (int)cvt_pk_bf16(v4, v5); pk.w = (int)cvt_pk_bf16(v6, v7);
      int chp = (c8 & ~7) | ((c8 & 7) ^ (row & 7));
      *(int4*)&Stile[row * 192 + chp * 8] = pk;
    }
  } else {
    const int p = l - 1, hh = p / 24, ww = p - hh * 24;
    #pragma unroll
    for (int j = 0; j < 3; ++j) {
      int c8 = cg + 8 * j;
      int cbase = c8 * 8;
      float acc8[8] = {};
      #pragma unroll
      for (int dh = 0; dh < 3; ++dh) {
        int y = hh + dh - 1;
        if ((unsigned)y >= 24u) continue;       // wave-uniform
        #pragma unroll
        for (int dw = 0; dw < 3; ++dw) {
          int xx = ww + dw - 1;
          if ((unsigned)xx >= 24u) continue;    // wave-uniform
          bf16x8 hv = *(const bf16x8*)
              &h[((size_t)(1 + y * 24 + xx) * 128 + bt) * 192 + cbase];
          const float* wp = w_base + (dh * 3 + dw) * 192 + cbase;
          float4 w0 = *(const float4*)wp, w1 = *(const float4*)(wp + 4);
          acc8[0] += bf2f((ushort_t)hv[0]) * w0.x;
          acc8[1] += bf2f((ushort_t)hv[1]) * w0.y;
          acc8[2] += bf2f((ushort_t)hv[2]) * w0.z;
          acc8[3] += bf2f((ushort_t)hv[3]) * w0.w;
          acc8[4] += bf2f((ushort_t)hv[4]) * w1.x;
          acc8[5] += bf2f((ushort_t)hv[5]) * w1.y;
          acc8[6] += bf2f((ushort_t)hv[6]) * w1.z;
          acc8[7] += bf2f((ushort_t)hv[7]) * w1.w;
        }
      }
      const float* ap = alpha + (size_t)bt * 192 + cbase;
      float4 a0 = *(const float4*)ap, a1 = *(const float4*)(ap + 4);
      const float* bp = b_conv + cbase;
      float4 c0 = *(const float4*)bp, c1 = *(const float4*)(bp + 4);
      float v0 = silu_g(acc8[0] * a0.x + c0.x), v1 = silu_g(acc8[1] * a0.y + c0.y);
      float v2 = silu_g(acc8[2] * a0.z + c0.z), v3 = silu_g(acc8[3] * a0.w + c0.w);
      float v4 = silu_g(acc8[4] * a1.x + c1.x), v5 = silu_g(acc8[5] * a1.y + c1.y);
      float v6 = silu_g(acc8[6] * a1.z + c1.z), v7 = silu_g(acc8[7] * a1.w + c1.w);
      int4 pk;
      pk.x = (int)cvt_pk_bf16(v0, v1); pk.y = (int)cvt_pk_bf16(v2, v3);
      pk.z = (int)cvt_pk_bf16(v4, v5); pk.w = (int)cvt_pk_bf16(v6, v7);
      int chp = (c8 & ~7) | ((c8 & 7) ^ (row & 7));
      *(int4*)&Stile[row * 192 + chp * 8] = pk;
    }
  }
  __syncthreads();   // the only block-wide barrier

  // ---- hoist A-fragments to registers (12 x bf16x8 = 48 VGPR) ----
  bf16x8 areg[6][2];
  #pragma unroll
  for (int kt = 0; kt < 6; ++kt) {
    #pragma unroll
    for (int fm = 0; fm < 2; ++fm) {
      int sr = wm * 32 + fm * 16 + lr;
      int kc = kt * 4 + lk8;
      int chp = (kc & ~7) | ((kc & 7) ^ (sr & 7));
      areg[kt][fm] = *(const bf16x8*)&Stile[sr * 192 + chp * 8];
    }
  }

  // ---- phase 2: 4 N-chunks, barrier-free, B straight from L2 ----
  const int cb = (lane >> 4) * 4;
  #pragma unroll 1
  for (int nc = 0; nc < 4; ++nc) {
    const int n0 = nc * 192;
    f32x4 acc[2][3] = {};
    #pragma unroll
    for (int kt = 0; kt < 6; ++kt) {
      bf16x8 bfv[3];
      #pragma unroll
      for (int fn = 0; fn < 3; ++fn)
        bfv[fn] = *(const bf16x8*)(Bt +
            (size_t)(n0 + wn * 48 + fn * 16 + lr) * 192 + kt * 32 + lk8 * 8);
      #pragma unroll
      for (int fm = 0; fm < 2; ++fm)
        #pragma unroll
        for (int fn = 0; fn < 3; ++fn)
          acc[fm][fn] = __builtin_amdgcn_mfma_f32_16x16x32_bf16(
              bfv[fn], areg[kt][fm], acc[fm][fn], 0, 0, 0);
    }
    #pragma unroll
    for (int fm = 0; fm < 2; ++fm) {
      int orow = l * 128 + bt0 + wm * 32 + fm * 16 + lr;
      #pragma unroll
      for (int fn = 0; fn < 3; ++fn) {
        int col = n0 + wn * 48 + fn * 16 + cb;
        float4 bv = *(const float4*)(bias + col);
        f32x4 o;
        o[0] = acc[fm][fn][0] + bv.x;
        o[1] = acc[fm][fn][1] + bv.y;
        o[2] = acc[fm][fn][2] + bv.z;
        o[3] = acc[fm][fn][3] + bv.w;
        *(f32x4*)&out[(size_t)orow * NTOT + col] = o;   // plain store (L2/L3)
      }
    }
  }
}

// ---------------------------------------------------------------------------
extern "C" void kernel_launch(void* const* d_in, const int* in_sizes, int n_in,
                              void* d_out, int out_size, void* d_ws, size_t ws_size,
                              hipStream_t stream) {
  (void)in_sizes; (void)n_in; (void)out_size; (void)ws_size;
  const float* x      = (const float*)d_in[0];
  const float* w_pre  = (const float*)d_in[1];
  const float* b_pre  = (const float*)d_in[2];
  const float* w_base = (const float*)d_in[3];
  const float* b_conv = (const float*)d_in[4];
  const float* w_g    = (const float*)d_in[5];
  const float* b_g    = (const float*)d_in[6];
  const float* w_a    = (const float*)d_in[7];
  const float* b_a    = (const float*)d_in[8];
  const float* w_b    = (const float*)d_in[9];
  const float* w_proj = (const float*)d_in[10];
  const float* b_proj = (const float*)d_in[11];

  float* out = (float*)d_out;
  char* ws = (char*)d_ws;
  short* w_preT  = (short*)(ws);                  //      0: 294912 B
  short* w_projT = (short*)(ws + 294912);         // 294912: 294912 B
  float* dbuf    = (float*)(ws + 589824);         // 589824:  98304 B
  float* alpha   = (float*)(ws + 688128);         // 688128:  98304 B
  ushort_t* h    = (ushort_t*)(ws + 786432);      // h bf16: 28360704 B
  // h in ws (NOT d_out): fused kernel reads h neighbors while writing out.

  prep_kernel<<<576, 256, 0, stream>>>(w_pre, w_proj, w_preT, w_projT);

  // GEMM1: h(bf16) = x @ w_pre + b_pre   (M=73856, K=768, N=192)
  gemm1_kernel<<<577, 512, 0, stream>>>(x, w_preT, b_pre, h);

  reduce_d_kernel<<<128, 384, 0, stream>>>(h, dbuf);
  small_path_kernel<<<16, 256, 0, stream>>>(dbuf, w_g, b_g, w_a, b_a, w_b, alpha);

  // fused dwconv+SiLU+GEMM2: out = silu(dwconv(h)*alpha+b_conv) @ w_proj + b
  fused_out_kernel<<<1154, 512, 0, stream>>>(h, alpha, w_base, b_conv,
                                             w_projT, b_proj, out);
}

// Round 12
// 232.267 us; speedup vs baseline: 1.1785x; 1.1785x over previous
//
#include <hip/hip_runtime.h>

#define DEV __device__ __forceinline__

typedef short bf16x8 __attribute__((ext_vector_type(8)));
typedef float f32x4  __attribute__((ext_vector_type(4)));
typedef unsigned short ushort_t;

// L=577, BT=128, D=768, B=16, T=8, H=W=24, CM=192, CR=48, K=3, M=L*BT=73856

DEV unsigned short f2bf(float f) {
  unsigned u = __float_as_uint(f);
  unsigned r = (u + 0x7fffu + ((u >> 16) & 1u)) >> 16;
  return (unsigned short)r;
}

DEV unsigned cvt_pk_bf16(float a, float b) {   // {lo:bf16(a), hi:bf16(b)} RNE
  unsigned r;
  asm("v_cvt_pk_bf16_f32 %0, %1, %2" : "=v"(r) : "v"(a), "v"(b));
  return r;
}

DEV float bf2f(unsigned short b) { return __uint_as_float((unsigned)b << 16); }

DEV float silu_g(float v) { return v / (1.f + __expf(-1.702f * v)); }

DEV void gload_lds16(const void* g, void* l) {
  __builtin_amdgcn_global_load_lds(
      (const __attribute__((address_space(1))) unsigned int*)g,
      (__attribute__((address_space(3))) unsigned int*)l, 16, 0, 0);
}

// ---------------------------------------------------------------------------
// Weight prep: transpose + cast to bf16, K-contiguous rows for MFMA B frags.
// ---------------------------------------------------------------------------
__global__ __launch_bounds__(256)
void prep_kernel(const float* __restrict__ w_pre, const float* __restrict__ w_proj,
                 short* __restrict__ w_preT, short* __restrict__ w_projT) {
  int i = blockIdx.x * 256 + threadIdx.x;
  if (i < 192 * 768) {
    int n = i / 768, k = i - n * 768;
    w_preT[i] = (short)f2bf(w_pre[k * 192 + n]);
    int n2 = i / 192, k2 = i - n2 * 192;
    w_projT[i] = (short)f2bf(w_proj[k2 * 768 + n2]);
  }
}

// ---------------------------------------------------------------------------
// GEMM1 (unchanged R7 structure): h(bf16)[M x 192] = x @ w_preT + b_pre
// ---------------------------------------------------------------------------
__global__ __launch_bounds__(512, 4)
void gemm1_kernel(const float* __restrict__ Af, const short* __restrict__ Bt,
                  const float* __restrict__ bias, ushort_t* __restrict__ C) {
  constexpr int BM = 128, BK = 64, KTOT = 768, NTOT = 192, NT = 12;
  __shared__ short As[2][BM * BK];   // 2x16 KB
  __shared__ short Bs[2][192 * BK];  // 2x24 KB

  const int tid  = threadIdx.x;
  const int wave = tid >> 6, lane = tid & 63;
  const int m0 = blockIdx.x * BM;
  const int wm = wave >> 2, wn = wave & 3;
  const int lr  = lane & 15;
  const int lk8 = lane >> 4;
  const int srow = lane >> 3;
  const int schunk = lane & 7;

  f32x4 acc[4][3] = {};
  float4 areg[2][2];

  auto loadA_f32 = [&](int kt) {
    #pragma unroll
    for (int s = 0; s < 2; ++s) {
      int id = tid + s * 512;
      int r = id >> 3, c = id & 7;
      int cg = c ^ (r & 7);
      const float* p = Af + (size_t)(m0 + r) * KTOT + kt + cg * 8;
      areg[s][0] = *(const float4*)p;
      areg[s][1] = *(const float4*)(p + 4);
    }
  };
  auto cvtStoreA = [&](int buf) {
    #pragma unroll
    for (int s = 0; s < 2; ++s) {
      int id = tid + s * 512;
      int r = id >> 3, c = id & 7;
      int4 w;
      w.x = (int)cvt_pk_bf16(areg[s][0].x, areg[s][0].y);
      w.y = (int)cvt_pk_bf16(areg[s][0].z, areg[s][0].w);
      w.z = (int)cvt_pk_bf16(areg[s][1].x, areg[s][1].y);
      w.w = (int)cvt_pk_bf16(areg[s][1].z, areg[s][1].w);
      *(int4*)&As[buf][r * 64 + c * 8] = w;
    }
  };
  auto stageB = [&](int kt, int buf) {
    #pragma unroll
    for (int j = 0; j < 3; ++j) {
      int rb8 = wave * 3 + j;
      int r = rb8 * 8 + srow;
      const short* src = Bt + (size_t)r * KTOT + kt + (schunk ^ srow) * 8;
      gload_lds16(src, (char*)Bs[buf] + rb8 * 1024);
    }
  };
  auto compute = [&](int buf) {
    #pragma unroll
    for (int ks = 0; ks < 2; ++ks) {
      int kc = ks * 4 + lk8;
      bf16x8 af[4], bfv[3];
      #pragma unroll
      for (int fm = 0; fm < 4; ++fm) {
        int row = wm * 64 + fm * 16 + lr;
        af[fm] = *(const bf16x8*)&As[buf][row * 64 + (kc ^ (row & 7)) * 8];
      }
      #pragma unroll
      for (int fn = 0; fn < 3; ++fn) {
        int row = wn * 48 + fn * 16 + lr;
        bfv[fn] = *(const bf16x8*)&Bs[buf][row * 64 + (kc ^ (row & 7)) * 8];
      }
      #pragma unroll
      for (int fm = 0; fm < 4; ++fm)
        #pragma unroll
        for (int fn = 0; fn < 3; ++fn)
          acc[fm][fn] = __builtin_amdgcn_mfma_f32_16x16x32_bf16(
              bfv[fn], af[fm], acc[fm][fn], 0, 0, 0);
    }
  };

  loadA_f32(0);
  cvtStoreA(0);
  stageB(0, 0);
  loadA_f32(BK);
  asm volatile("s_waitcnt vmcnt(4) lgkmcnt(0)" ::: "memory");
  __builtin_amdgcn_s_barrier();

  #pragma unroll
  for (int t = 0; t < NT; ++t) {
    const int cur = t & 1, nxt = cur ^ 1;
    if (t + 1 < NT) {
      stageB((t + 1) * BK, nxt);
      cvtStoreA(nxt);
      if (t + 2 < NT) loadA_f32((t + 2) * BK);
    }
    compute(cur);
    if (t + 1 < NT) {
      if (t + 2 < NT)
        asm volatile("s_waitcnt vmcnt(4) lgkmcnt(0)" ::: "memory");
      else
        asm volatile("s_waitcnt vmcnt(0) lgkmcnt(0)" ::: "memory");
      __builtin_amdgcn_s_barrier();
    }
  }

  const int cb = (lane >> 4) * 4;
  #pragma unroll
  for (int fm = 0; fm < 4; ++fm) {
    int row = m0 + wm * 64 + fm * 16 + lr;
    #pragma unroll
    for (int fn = 0; fn < 3; ++fn) {
      int col = wn * 48 + fn * 16 + cb;
      float4 bv = *(const float4*)(bias + col);
      int2 w;
      w.x = (int)cvt_pk_bf16(acc[fm][fn][0] + bv.x, acc[fm][fn][1] + bv.y);
      w.y = (int)cvt_pk_bf16(acc[fm][fn][2] + bv.z, acc[fm][fn][3] + bv.w);
      *(int2*)&C[(size_t)row * NTOT + col] = w;
    }
  }
}

// ---------------------------------------------------------------------------
// d[bt][c] = mean over l=1..576 of h_bf16[(l*128+bt)*192 + c]
// ---------------------------------------------------------------------------
__global__ __launch_bounds__(384)
void reduce_d_kernel(const ushort_t* __restrict__ h, float* __restrict__ d) {
  const int bt = blockIdx.x, tid = threadIdx.x;
  const int slice = tid / 24, c8 = tid % 24;
  __shared__ float part[16][192];
  float sum[8] = {};
  #pragma unroll 4
  for (int i = 0; i < 36; ++i) {
    int l = 1 + slice * 36 + i;
    bf16x8 v = *(const bf16x8*)&h[((size_t)l * 128 + bt) * 192 + c8 * 8];
    #pragma unroll
    for (int j = 0; j < 8; ++j) sum[j] += bf2f((unsigned short)v[j]);
  }
  #pragma unroll
  for (int j = 0; j < 8; ++j) part[slice][c8 * 8 + j] = sum[j];
  __syncthreads();
  if (tid < 192) {
    float s = 0.f;
    #pragma unroll
    for (int sl = 0; sl < 16; ++sl) s += part[sl][tid];
    d[bt * 192 + tid] = s * (1.f / 576.f);
  }
}

// ---------------------------------------------------------------------------
// Small path (unchanged): one block per b, 256 thr, LDS-staged bf16 weights.
// ---------------------------------------------------------------------------
__global__ __launch_bounds__(256)
void small_path_kernel(const float* __restrict__ d,
                       const float* __restrict__ w_g, const float* __restrict__ b_g,
                       const float* __restrict__ w_a, const float* __restrict__ b_a,
                       const float* __restrict__ w_b,
                       float* __restrict__ alpha) {
  const int b = blockIdx.x, tid = threadIdx.x;
  __shared__ unsigned short wg_buf[36864];   // 72 KB (w_g, then w_b)
  __shared__ unsigned short wa_buf[27648];   // 54 KB
  __shared__ float e[8][192];
  __shared__ float md[192];
  __shared__ float a[8][48];

  #pragma unroll
  for (int it = 0; it < 36; ++it) {
    int i = tid + it * 256;
    float4 v = *(const float4*)(w_g + i * 4);
    int2 w;
    w.x = (int)cvt_pk_bf16(v.x, v.y);
    w.y = (int)cvt_pk_bf16(v.z, v.w);
    *(int2*)&wg_buf[i * 4] = w;
  }
  #pragma unroll
  for (int it = 0; it < 27; ++it) {
    int i = tid + it * 256;
    float4 v = *(const float4*)(w_a + i * 4);
    int2 w;
    w.x = (int)cvt_pk_bf16(v.x, v.y);
    w.y = (int)cvt_pk_bf16(v.z, v.w);
    *(int2*)&wa_buf[i * 4] = w;
  }
  for (int i = tid; i < 384; i += 256)
    *(float4*)((float*)e + i * 4) = *(const float4*)(d + (size_t)b * 1536 + i * 4);
  __syncthreads();

  if (tid < 192) {
    float m = 0.f;
    #pragma unroll
    for (int t = 0; t < 8; ++t) m += e[t][tid];
    md[tid] = m * 0.125f;
  }
  __syncthreads();

  if (tid < 192) {
    float accg = b_g[tid];
    #pragma unroll 8
    for (int k = 0; k < 192; ++k)
      accg += md[k] * bf2f(wg_buf[k * 192 + tid]);
    #pragma unroll
    for (int t = 0; t < 8; ++t) e[t][tid] += accg;
  }
  __syncthreads();

  #pragma unroll
  for (int it = 0; it < 27; ++it) {
    int i = tid + it * 256;
    float4 v = *(const float4*)(w_b + i * 4);
    int2 w;
    w.x = (int)cvt_pk_bf16(v.x, v.y);
    w.y = (int)cvt_pk_bf16(v.z, v.w);
    *(int2*)&wg_buf[i * 4] = w;
  }
  for (int o = tid; o < 384; o += 256) {
    int t = o / 48, r = o - t * 48;
    float acc = b_a[r];
    #pragma unroll
    for (int dt = 0; dt < 3; ++dt) {
      int tt = t + dt - 1;
      if ((unsigned)tt < 8u) {
        #pragma unroll 8
        for (int k = 0; k < 192; ++k)
          acc += e[tt][k] * bf2f(wa_buf[(dt * 192 + k) * 48 + r]);
      }
    }
    a[t][r] = fmaxf(acc, 0.f);
  }
  __syncthreads();

  if (tid < 192) {
    #pragma unroll
    for (int t = 0; t < 8; ++t) {
      float acc = 1.0f;
      #pragma unroll
      for (int dt = 0; dt < 3; ++dt) {
        int tt = t + dt - 1;
        if ((unsigned)tt < 8u) {
          #pragma unroll 8
          for (int r = 0; r < 48; ++r)
            acc += a[tt][r] * bf2f(wg_buf[(dt * 48 + r) * 192 + tid]);
        }
      }
      alpha[(size_t)(b * 8 + t) * 192 + tid] = acc;
    }
  }
}

// ---------------------------------------------------------------------------
// FUSED dwconv+SiLU+GEMM2 v3: MLP-batched loads.
// BM=64, grid (577 l x 2), 512 thr = 8 waves (2M x 4N), wave tile 32x48.
// Phase 1: interior fast path issues all 9 h-taps per j before FMAs.
// Phase 2: all 18 B-fragments batch-issued into regs before 36 MFMAs;
// A-frags from LDS inline. NT stores (keeps L3 clean - R11 lesson).
// ---------------------------------------------------------------------------
__global__ __launch_bounds__(512, 3)
void fused_out_kernel(const ushort_t* __restrict__ h, const float* __restrict__ alpha,
                      const float* __restrict__ w_base, const float* __restrict__ b_conv,
                      const short* __restrict__ Bt, const float* __restrict__ bias,
                      float* __restrict__ out) {
  constexpr int NTOT = 768;
  __shared__ ushort_t Stile[64 * 192];   // 24 KB, swizzled 16B chunks

  const int tid  = threadIdx.x;
  const int l    = blockIdx.x >> 1;
  const int bt0  = (blockIdx.x & 1) * 64;
  const int wave = tid >> 6, lane = tid & 63;
  const int wm = wave >> 2, wn = wave & 3;
  const int lr = lane & 15, lk8 = lane >> 4;

  // ---- phase 1: s-subtile (64 bt rows x 192 c) ----
  const int row = tid >> 3;               // 0..63
  const int cg  = tid & 7;
  const int bt  = bt0 + row;
  if (l == 0) {
    #pragma unroll
    for (int j = 0; j < 3; ++j) {
      int c8 = cg + 8 * j;                // 0..23
      bf16x8 hv = *(const bf16x8*)&h[(size_t)bt * 192 + c8 * 8];
      float v0 = silu_g(bf2f((ushort_t)hv[0])), v1 = silu_g(bf2f((ushort_t)hv[1]));
      float v2 = silu_g(bf2f((ushort_t)hv[2])), v3 = silu_g(bf2f((ushort_t)hv[3]));
      float v4 = silu_g(bf2f((ushort_t)hv[4])), v5 = silu_g(bf2f((ushort_t)hv[5]));
      float v6 = silu_g(bf2f((ushort_t)hv[6])), v7 = silu_g(bf2f((ushort_t)hv[7]));
      int4 pk;
      pk.x = (int)cvt_pk_bf16(v0, v1); pk.y = (int)cvt_pk_bf16(v2, v3);
      pk.z = (int)cvt_pk_bf16(v4, v5); pk.w = (int)cvt_pk_bf16(v6, v7);
      int chp = (c8 & ~7) | ((c8 & 7) ^ (row & 7));
      *(int4*)&Stile[row * 192 + chp * 8] = pk;
    }
  } else {
    const int p = l - 1, hh = p / 24, ww = p - hh * 24;
    const bool interior = (hh > 0) & (hh < 23) & (ww > 0) & (ww < 23);
    if (interior) {
      // fast path (84% of blocks): batch all 9 taps -> 9 loads in flight
      #pragma unroll
      for (int j = 0; j < 3; ++j) {
        int c8 = cg + 8 * j;
        int cbase = c8 * 8;
        bf16x8 hv[9];
        #pragma unroll
        for (int dh = 0; dh < 3; ++dh)
          #pragma unroll
          for (int dw = 0; dw < 3; ++dw)
            hv[dh * 3 + dw] = *(const bf16x8*)
                &h[((size_t)(1 + (hh + dh - 1) * 24 + (ww + dw - 1)) * 128 + bt) * 192 + cbase];
        float acc8[8] = {};
        #pragma unroll
        for (int t9 = 0; t9 < 9; ++t9) {
          const float* wp = w_base + t9 * 192 + cbase;
          float4 w0 = *(const float4*)wp, w1 = *(const float4*)(wp + 4);
          acc8[0] += bf2f((ushort_t)hv[t9][0]) * w0.x;
          acc8[1] += bf2f((ushort_t)hv[t9][1]) * w0.y;
          acc8[2] += bf2f((ushort_t)hv[t9][2]) * w0.z;
          acc8[3] += bf2f((ushort_t)hv[t9][3]) * w0.w;
          acc8[4] += bf2f((ushort_t)hv[t9][4]) * w1.x;
          acc8[5] += bf2f((ushort_t)hv[t9][5]) * w1.y;
          acc8[6] += bf2f((ushort_t)hv[t9][6]) * w1.z;
          acc8[7] += bf2f((ushort_t)hv[t9][7]) * w1.w;
        }
        const float* ap = alpha + (size_t)bt * 192 + cbase;
        float4 a0 = *(const float4*)ap, a1 = *(const float4*)(ap + 4);
        const float* bp = b_conv + cbase;
        float4 c0 = *(const float4*)bp, c1 = *(const float4*)(bp + 4);
        float v0 = silu_g(acc8[0] * a0.x + c0.x), v1 = silu_g(acc8[1] * a0.y + c0.y);
        float v2 = silu_g(acc8[2] * a0.z + c0.z), v3 = silu_g(acc8[3] * a0.w + c0.w);
        float v4 = silu_g(acc8[4] * a1.x + c1.x), v5 = silu_g(acc8[5] * a1.y + c1.y);
        float v6 = silu_g(acc8[6] * a1.z + c1.z), v7 = silu_g(acc8[7] * a1.w + c1.w);
        int4 pk;
        pk.x = (int)cvt_pk_bf16(v0, v1); pk.y = (int)cvt_pk_bf16(v2, v3);
        pk.z = (int)cvt_pk_bf16(v4, v5); pk.w = (int)cvt_pk_bf16(v6, v7);
        int chp = (c8 & ~7) | ((c8 & 7) ^ (row & 7));
        *(int4*)&Stile[row * 192 + chp * 8] = pk;
      }
    } else {
      // border path (generic, wave-uniform tap validity)
      #pragma unroll
      for (int j = 0; j < 3; ++j) {
        int c8 = cg + 8 * j;
        int cbase = c8 * 8;
        float acc8[8] = {};
        #pragma unroll
        for (int dh = 0; dh < 3; ++dh) {
          int y = hh + dh - 1;
          if ((unsigned)y >= 24u) continue;
          #pragma unroll
          for (int dw = 0; dw < 3; ++dw) {
            int xx = ww + dw - 1;
            if ((unsigned)xx >= 24u) continue;
            bf16x8 hv = *(const bf16x8*)
                &h[((size_t)(1 + y * 24 + xx) * 128 + bt) * 192 + cbase];
            const float* wp = w_base + (dh * 3 + dw) * 192 + cbase;
            float4 w0 = *(const float4*)wp, w1 = *(const float4*)(wp + 4);
            acc8[0] += bf2f((ushort_t)hv[0]) * w0.x;
            acc8[1] += bf2f((ushort_t)hv[1]) * w0.y;
            acc8[2] += bf2f((ushort_t)hv[2]) * w0.z;
            acc8[3] += bf2f((ushort_t)hv[3]) * w0.w;
            acc8[4] += bf2f((ushort_t)hv[4]) * w1.x;
            acc8[5] += bf2f((ushort_t)hv[5]) * w1.y;
            acc8[6] += bf2f((ushort_t)hv[6]) * w1.z;
            acc8[7] += bf2f((ushort_t)hv[7]) * w1.w;
          }
        }
        const float* ap = alpha + (size_t)bt * 192 + cbase;
        float4 a0 = *(const float4*)ap, a1 = *(const float4*)(ap + 4);
        const float* bp = b_conv + cbase;
        float4 c0 = *(const float4*)bp, c1 = *(const float4*)(bp + 4);
        float v0 = silu_g(acc8[0] * a0.x + c0.x), v1 = silu_g(acc8[1] * a0.y + c0.y);
        float v2 = silu_g(acc8[2] * a0.z + c0.z), v3 = silu_g(acc8[3] * a0.w + c0.w);
        float v4 = silu_g(acc8[4] * a1.x + c1.x), v5 = silu_g(acc8[5] * a1.y + c1.y);
        float v6 = silu_g(acc8[6] * a1.z + c1.z), v7 = silu_g(acc8[7] * a1.w + c1.w);
        int4 pk;
        pk.x = (int)cvt_pk_bf16(v0, v1); pk.y = (int)cvt_pk_bf16(v2, v3);
        pk.z = (int)cvt_pk_bf16(v4, v5); pk.w = (int)cvt_pk_bf16(v6, v7);
        int chp = (c8 & ~7) | ((c8 & 7) ^ (row & 7));
        *(int4*)&Stile[row * 192 + chp * 8] = pk;
      }
    }
  }
  __syncthreads();   // the only block-wide barrier

  // ---- phase 2: 4 N-chunks, batch-issued B loads, A from LDS ----
  const int cb = (lane >> 4) * 4;
  #pragma unroll 1
  for (int nc = 0; nc < 4; ++nc) {
    const int n0 = nc * 192;
    // batch-issue ALL 18 B-fragment loads (held in 72 VGPRs, 18 in flight)
    bf16x8 bfv[6][3];
    #pragma unroll
    for (int kt = 0; kt < 6; ++kt)
      #pragma unroll
      for (int fn = 0; fn < 3; ++fn)
        bfv[kt][fn] = *(const bf16x8*)(Bt +
            (size_t)(n0 + wn * 48 + fn * 16 + lr) * 192 + kt * 32 + lk8 * 8);

    f32x4 acc[2][3] = {};
    #pragma unroll
    for (int kt = 0; kt < 6; ++kt) {
      bf16x8 af[2];
      #pragma unroll
      for (int fm = 0; fm < 2; ++fm) {
        int sr = wm * 32 + fm * 16 + lr;
        int kc = kt * 4 + lk8;
        int chp = (kc & ~7) | ((kc & 7) ^ (sr & 7));
        af[fm] = *(const bf16x8*)&Stile[sr * 192 + chp * 8];
      }
      #pragma unroll
      for (int fm = 0; fm < 2; ++fm)
        #pragma unroll
        for (int fn = 0; fn < 3; ++fn)
          acc[fm][fn] = __builtin_amdgcn_mfma_f32_16x16x32_bf16(
              bfv[kt][fn], af[fm], acc[fm][fn], 0, 0, 0);
    }

    #pragma unroll
    for (int fm = 0; fm < 2; ++fm) {
      int orow = l * 128 + bt0 + wm * 32 + fm * 16 + lr;
      #pragma unroll
      for (int fn = 0; fn < 3; ++fn) {
        int col = n0 + wn * 48 + fn * 16 + cb;
        float4 bv = *(const float4*)(bias + col);
        f32x4 o;
        o[0] = acc[fm][fn][0] + bv.x;
        o[1] = acc[fm][fn][1] + bv.y;
        o[2] = acc[fm][fn][2] + bv.z;
        o[3] = acc[fm][fn][3] + bv.w;
        __builtin_nontemporal_store(o, (f32x4*)&out[(size_t)orow * NTOT + col]);
      }
    }
  }
}

// ---------------------------------------------------------------------------
extern "C" void kernel_launch(void* const* d_in, const int* in_sizes, int n_in,
                              void* d_out, int out_size, void* d_ws, size_t ws_size,
                              hipStream_t stream) {
  (void)in_sizes; (void)n_in; (void)out_size; (void)ws_size;
  const float* x      = (const float*)d_in[0];
  const float* w_pre  = (const float*)d_in[1];
  const float* b_pre  = (const float*)d_in[2];
  const float* w_base = (const float*)d_in[3];
  const float* b_conv = (const float*)d_in[4];
  const float* w_g    = (const float*)d_in[5];
  const float* b_g    = (const float*)d_in[6];
  const float* w_a    = (const float*)d_in[7];
  const float* b_a    = (const float*)d_in[8];
  const float* w_b    = (const float*)d_in[9];
  const float* w_proj = (const float*)d_in[10];
  const float* b_proj = (const float*)d_in[11];

  float* out = (float*)d_out;
  char* ws = (char*)d_ws;
  short* w_preT  = (short*)(ws);                  //      0: 294912 B
  short* w_projT = (short*)(ws + 294912);         // 294912: 294912 B
  float* dbuf    = (float*)(ws + 589824);         // 589824:  98304 B
  float* alpha   = (float*)(ws + 688128);         // 688128:  98304 B
  ushort_t* h    = (ushort_t*)(ws + 786432);      // h bf16: 28360704 B
  // h in ws (NOT d_out): fused kernel reads h neighbors while writing out.

  prep_kernel<<<576, 256, 0, stream>>>(w_pre, w_proj, w_preT, w_projT);

  // GEMM1: h(bf16) = x @ w_pre + b_pre   (M=73856, K=768, N=192)
  gemm1_kernel<<<577, 512, 0, stream>>>(x, w_preT, b_pre, h);

  reduce_d_kernel<<<128, 384, 0, stream>>>(h, dbuf);
  small_path_kernel<<<16, 256, 0, stream>>>(dbuf, w_g, b_g, w_a, b_a, w_b, alpha);

  // fused dwconv+SiLU+GEMM2: out = silu(dwconv(h)*alpha+b_conv) @ w_proj + b
  fused_out_kernel<<<1154, 512, 0, stream>>>(h, alpha, w_base, b_conv,
                                             w_projT, b_proj, out);
}